// Round 6
// baseline (154.834 us; speedup 1.0000x reference)
//
#include <hip/hip_runtime.h>
#include <math.h>

#define NE 8
#define NT 512
#define NH 1024
#define NF 2816
#define TWO_F (2*NF)      // 5632
#define HP (NH/8)         // 128 packed rows for w13
#define FP (NF/8)         // 352 packed rows for w2
#define H_GROUPS 8
#define F_GROUPS 22
#define INV254 (1.0f/254.0f)

typedef __attribute__((ext_vector_type(4))) int   int4v;
typedef __attribute__((ext_vector_type(4))) float f32x4;
typedef __attribute__((ext_vector_type(8))) short short8;

__device__ inline short f2bf(float f) {
    unsigned u = __float_as_uint(f);
    u += 0x7FFFu + ((u >> 16) & 1u);   // RNE
    return (short)(u >> 16);
}
__device__ inline float bf2f(short s) {
    return __uint_as_float(((unsigned)(unsigned short)s) << 16);
}

// 16 nibbles (rows kp, kp+1 packed ints) -> 16 int8 bytes = (nib - 8)
__device__ inline int4v unpack16(int q0, int q1) {
    int e0 = q0 & 0x0F0F0F0F, o0 = ((unsigned)q0 >> 4) & 0x0F0F0F0F;
    int e1 = q1 & 0x0F0F0F0F, o1 = ((unsigned)q1 >> 4) & 0x0F0F0F0F;
    int4v b;
    b[0] = (__builtin_amdgcn_perm(o0, e0, 0x05010400) + 0x78787878) ^ 0x80808080;
    b[1] = (__builtin_amdgcn_perm(o0, e0, 0x07030602) + 0x78787878) ^ 0x80808080;
    b[2] = (__builtin_amdgcn_perm(o1, e1, 0x05010400) + 0x78787878) ^ 0x80808080;
    b[3] = (__builtin_amdgcn_perm(o1, e1, 0x07030602) + 0x78787878) ^ 0x80808080;
    return b;
}

__device__ inline int pack4(const int* b) {
    return (b[0] & 255) | ((b[1] & 255) << 8) | ((b[2] & 255) << 16) | ((b[3] & 255) << 24);
}

// ---- routing (softmax->top2->renorm) + stable binning + prefix + rowmap ----
__global__ __launch_bounds__(512) void route_bin_kernel(
        const float* __restrict__ logits,
        float* __restrict__ topk_w,
        int* __restrict__ counts,
        int* __restrict__ offs,
        int* __restrict__ tok_list,
        int* __restrict__ rowmap) {
    __shared__ int sh_e[2 * NT];
    __shared__ int sh_cnt[NE], sh_off[NE];
    const int t = threadIdx.x;   // one token per thread, NT==512
    float l[NE];
#pragma unroll
    for (int e = 0; e < NE; ++e) l[e] = logits[t * NE + e];
    int i0 = 0; float v0 = l[0];
#pragma unroll
    for (int e = 1; e < NE; ++e) { if (l[e] > v0) { v0 = l[e]; i0 = e; } }
    int i1 = -1; float v1 = -INFINITY;
#pragma unroll
    for (int e = 0; e < NE; ++e) {
        if (e == i0) continue;
        if (l[e] > v1) { v1 = l[e]; i1 = e; }
    }
    float e1 = expf(v1 - v0);
    float inv = 1.0f / (1.0f + e1);
    topk_w[t * 2 + 0] = inv;
    topk_w[t * 2 + 1] = e1 * inv;
    sh_e[t * 2 + 0] = i0;
    sh_e[t * 2 + 1] = i1;
    __syncthreads();
    const int w = t >> 6, lane = t & 63;
    int base = 0;
    for (int chunk = 0; chunk < 16; ++chunk) {
        int j = chunk * 64 + lane;
        bool m = (sh_e[j] == w);
        unsigned long long mask = __ballot(m);
        if (m) {
            int pos = base + __popcll(mask & ((1ull << lane) - 1ull));
            tok_list[w * NT + pos] = j;   // j = t*2 + slot
        }
        base += __popcll(mask);
    }
    if (lane == 0) { counts[w] = base; sh_cnt[w] = base; }
    __syncthreads();
    if (t == 0) {
        int o = 0;
#pragma unroll
        for (int e = 0; e < NE; ++e) { sh_off[e] = o; offs[e] = o; o += sh_cnt[e]; }
    }
    __syncthreads();
    const int myoff = sh_off[w];
    for (int i = lane; i < sh_cnt[w]; i += 64)
        rowmap[myoff + i] = tok_list[w * NT + i];   // own wave's writes: safe
}

// -------- gather + x -> dual int8 (hi + lo/254), per-row scale, sorted ------
__global__ __launch_bounds__(256) void quant_x_kernel(const float* __restrict__ x,
                                                      const int* __restrict__ rowmap,
                                                      char* __restrict__ xh,
                                                      char* __restrict__ xl,
                                                      float* __restrict__ sx) {
    __shared__ float wmax[4];
    const int r = blockIdx.x;              // sorted row
    const int t = rowmap[r] >> 1;
    const int tid = threadIdx.x;
    f32x4 v = *(const f32x4*)(x + (size_t)t * NH + tid * 4);
    float m = fmaxf(fmaxf(fabsf(v[0]), fabsf(v[1])), fmaxf(fabsf(v[2]), fabsf(v[3])));
#pragma unroll
    for (int off = 32; off >= 1; off >>= 1)
        m = fmaxf(m, __shfl_xor(m, off, 64));
    if ((tid & 63) == 0) wmax[tid >> 6] = m;
    __syncthreads();
    float amax = fmaxf(fmaxf(wmax[0], wmax[1]), fmaxf(wmax[2], wmax[3]));
    float scale = (amax > 0.f) ? amax / 127.f : 0.f;
    float invs  = (amax > 0.f) ? 127.f / amax : 0.f;
    if (tid == 0) sx[r] = scale;
    int bh[4], bl[4];
#pragma unroll
    for (int j = 0; j < 4; ++j) {
        float xs = v[j] * invs;
        float qh = rintf(xs);
        qh = fminf(fmaxf(qh, -127.f), 127.f);
        float ql = rintf((xs - qh) * 254.f);
        ql = fminf(fmaxf(ql, -127.f), 127.f);
        bh[j] = (int)qh; bl[j] = (int)ql;
    }
    ((int*)xh)[r * (NH / 4) + tid] = pack4(bh);
    ((int*)xl)[r * (NH / 4) + tid] = pack4(bl);
}

// ------- GEMM1 + silu fused (dual int8): block 128M x 32Fpair, 4-wave M-split
// physical col = cF + lr*2 + ns  (b64 weight col-pairs; all waves share cols)
__global__ __launch_bounds__(256) void gemm1_act_kernel(
        const char*  __restrict__ xh,
        const char*  __restrict__ xl,
        const float* __restrict__ sx,
        const int*   __restrict__ w13q,
        const float* __restrict__ s13,
        const int*   __restrict__ counts,
        const int*   __restrict__ offs,
        short* __restrict__ a_s) {
    const int e = blockIdx.z;
    const int me = counts[e];
    const int mtile = blockIdx.y;
    if (mtile * 128 >= me) return;
    const int base = offs[e];
    const int tid = threadIdx.x;
    const int w = tid >> 6, l = tid & 63;
    const int lr = l & 15, kg = l >> 4;
    const int rb = mtile * 128 + w * 32;
    const int c0 = blockIdx.x * 32 + lr * 2;   // g col pair; u at +NF

    const char* pAh[2]; const char* pAl[2];
#pragma unroll
    for (int ms = 0; ms < 2; ++ms) {
        int i = rb + ms * 16 + lr;
        if (i >= me) i = me - 1;
        pAh[ms] = xh + (size_t)(base + i) * NH;
        pAl[ms] = xl + (size_t)(base + i) * NH;
    }

    f32x4 fg[2][2], fu[2][2];
#pragma unroll
    for (int ms = 0; ms < 2; ++ms)
#pragma unroll
        for (int ns = 0; ns < 2; ++ns) { fg[ms][ns] = (f32x4)0.f; fu[ms][ns] = (f32x4)0.f; }

    const int* wbase = w13q + (size_t)e * HP * TWO_F;
    const float* sbase = s13 + (size_t)e * H_GROUPS * TWO_F;

#pragma unroll 2
    for (int kb = 0; kb < H_GROUPS; ++kb) {
        const float2 scg = *(const float2*)(sbase + (size_t)kb * TWO_F + c0);
        const float2 scu = *(const float2*)(sbase + (size_t)kb * TWO_F + NF + c0);
        int4v hg[2][2], lg[2][2], hu[2][2], lu[2][2];
#pragma unroll
        for (int ms = 0; ms < 2; ++ms)
#pragma unroll
            for (int ns = 0; ns < 2; ++ns) {
                hg[ms][ns] = (int4v)0; lg[ms][ns] = (int4v)0;
                hu[ms][ns] = (int4v)0; lu[ms][ns] = (int4v)0;
            }
#pragma unroll
        for (int ks = 0; ks < 2; ++ks) {
            const int k0 = kb * 128 + ks * 64 + kg * 16;
            int4v ah[2], al[2];
#pragma unroll
            for (int ms = 0; ms < 2; ++ms) {
                ah[ms] = *(const int4v*)(pAh[ms] + k0);
                al[ms] = *(const int4v*)(pAl[ms] + k0);
            }
            const int kp = kb * 16 + ks * 8 + kg * 2;
            const int2 g0 = *(const int2*)(wbase + (size_t)kp * TWO_F + c0);
            const int2 g1 = *(const int2*)(wbase + (size_t)(kp + 1) * TWO_F + c0);
            const int2 u0 = *(const int2*)(wbase + (size_t)kp * TWO_F + NF + c0);
            const int2 u1 = *(const int2*)(wbase + (size_t)(kp + 1) * TWO_F + NF + c0);
            int4v bg[2], bu[2];
            bg[0] = unpack16(g0.x, g1.x); bg[1] = unpack16(g0.y, g1.y);
            bu[0] = unpack16(u0.x, u1.x); bu[1] = unpack16(u0.y, u1.y);
#pragma unroll
            for (int ns = 0; ns < 2; ++ns)
#pragma unroll
                for (int ms = 0; ms < 2; ++ms) {
                    hg[ms][ns] = __builtin_amdgcn_mfma_i32_16x16x64_i8(ah[ms], bg[ns], hg[ms][ns], 0, 0, 0);
                    lg[ms][ns] = __builtin_amdgcn_mfma_i32_16x16x64_i8(al[ms], bg[ns], lg[ms][ns], 0, 0, 0);
                    hu[ms][ns] = __builtin_amdgcn_mfma_i32_16x16x64_i8(ah[ms], bu[ns], hu[ms][ns], 0, 0, 0);
                    lu[ms][ns] = __builtin_amdgcn_mfma_i32_16x16x64_i8(al[ms], bu[ns], lu[ms][ns], 0, 0, 0);
                }
        }
        const float sg2[2] = { scg.x * INV254, scg.y * INV254 };
        const float su2[2] = { scu.x * INV254, scu.y * INV254 };
#pragma unroll
        for (int ms = 0; ms < 2; ++ms)
#pragma unroll
            for (int ns = 0; ns < 2; ++ns)
#pragma unroll
                for (int r = 0; r < 4; ++r) {
                    fg[ms][ns][r] += sg2[ns] * (float)(__mul24(hg[ms][ns][r], 254) + lg[ms][ns][r]);
                    fu[ms][ns][r] += su2[ns] * (float)(__mul24(hu[ms][ns][r], 254) + lu[ms][ns][r]);
                }
    }
    // epilogue: C row = kg*4 + r (+ms*16); cols c0 (ns=0), c0+1 (ns=1)
#pragma unroll
    for (int ms = 0; ms < 2; ++ms) {
#pragma unroll
        for (int r = 0; r < 4; ++r) {
            const int orow = rb + ms * 16 + kg * 4 + r;
            if (orow < me) {
                const int rg = base + orow;
                const float sxm = sx[rg];
                float av[2];
#pragma unroll
                for (int ns = 0; ns < 2; ++ns) {
                    const float g = sxm * fg[ms][ns][r];
                    const float u = sxm * fu[ms][ns][r];
                    av[ns] = (g / (1.0f + __expf(-g))) * u;
                }
                const unsigned pk = (unsigned)(unsigned short)f2bf(av[0])
                                  | ((unsigned)(unsigned short)f2bf(av[1]) << 16);
                *(unsigned*)(a_s + (size_t)rg * NF + c0) = pk;
            }
        }
    }
}

// -------- a (bf16, sorted) -> dual int8, per-row scale --------
__global__ __launch_bounds__(256) void quant_a_kernel(const short* __restrict__ a_s,
                                                      char* __restrict__ ah,
                                                      char* __restrict__ al,
                                                      float* __restrict__ sxa) {
    __shared__ float wmax[4];
    const int row = blockIdx.x;            // sorted row 0..1023
    const int tid = threadIdx.x;
    const short* src = a_s + (size_t)row * NF;
    float m = 0.f;
    short8 v[2];
#pragma unroll
    for (int it = 0; it < 2; ++it) {
        const int i = tid + it * 256;
        if (i < NF / 8) {
            v[it] = *(const short8*)(src + i * 8);
#pragma unroll
            for (int j = 0; j < 8; ++j) m = fmaxf(m, fabsf(bf2f(v[it][j])));
        }
    }
#pragma unroll
    for (int off = 32; off >= 1; off >>= 1)
        m = fmaxf(m, __shfl_xor(m, off, 64));
    if ((tid & 63) == 0) wmax[tid >> 6] = m;
    __syncthreads();
    float amax = fmaxf(fmaxf(wmax[0], wmax[1]), fmaxf(wmax[2], wmax[3]));
    float scale = (amax > 0.f) ? amax / 127.f : 0.f;
    float invs  = (amax > 0.f) ? 127.f / amax : 0.f;
    if (tid == 0) sxa[row] = scale;
#pragma unroll
    for (int it = 0; it < 2; ++it) {
        const int i = tid + it * 256;
        if (i < NF / 8) {
            int dh[2], dl[2];
#pragma unroll
            for (int h = 0; h < 2; ++h) {
                int bh[4], bl[4];
#pragma unroll
                for (int j = 0; j < 4; ++j) {
                    float xs = bf2f(v[it][h * 4 + j]) * invs;
                    float qh = rintf(xs);
                    qh = fminf(fmaxf(qh, -127.f), 127.f);
                    float ql = rintf((xs - qh) * 254.f);
                    ql = fminf(fmaxf(ql, -127.f), 127.f);
                    bh[j] = (int)qh; bl[j] = (int)ql;
                }
                dh[h] = pack4(bh); dl[h] = pack4(bl);
            }
            *(int2*)(ah + (size_t)row * NF + i * 8) = make_int2(dh[0], dh[1]);
            *(int2*)(al + (size_t)row * NF + i * 8) = make_int2(dl[0], dl[1]);
        }
    }
}

// ------- GEMM2 (dual int8): block 64M x 32N, 4-wave K-split + LDS reduce ----
__global__ __launch_bounds__(256) void gemm2_kernel(
        const char*  __restrict__ ahq,
        const char*  __restrict__ alq,
        const float* __restrict__ sxa,
        const int*   __restrict__ w2q,
        const float* __restrict__ s2,
        const int*   __restrict__ counts,
        const int*   __restrict__ offs,
        const int*   __restrict__ rowmap,
        const float* __restrict__ topk_w,
        float* __restrict__ out) {
    __shared__ float red[3][64][33];
    const int e = blockIdx.z;
    const int me = counts[e];
    const int mtile = blockIdx.y;
    if (mtile * 64 >= me) return;
    const int base = offs[e];
    const int tid = threadIdx.x;
    const int kh = tid >> 6, l = tid & 63;
    const int lr = l & 15, kg = l >> 4;
    const int rb = mtile * 64;
    const int c0 = blockIdx.x * 32 + lr * 2;

    const char* pAh[4]; const char* pAl[4];
#pragma unroll
    for (int ms = 0; ms < 4; ++ms) {
        int i = rb + ms * 16 + lr;
        if (i >= me) i = me - 1;
        pAh[ms] = ahq + (size_t)(base + i) * NF;
        pAl[ms] = alq + (size_t)(base + i) * NF;
    }

    f32x4 facc[4][2];
#pragma unroll
    for (int ms = 0; ms < 4; ++ms)
#pragma unroll
        for (int ns = 0; ns < 2; ++ns) facc[ms][ns] = (f32x4)0.f;

    const int* wbase = w2q + (size_t)e * FP * NH;
    const float* sbase = s2 + (size_t)e * F_GROUPS * NH;

    for (int g = kh; g < F_GROUPS; g += 4) {
        const float2 sc = *(const float2*)(sbase + (size_t)g * NH + c0);
        const float sc2[2] = { sc.x * INV254, sc.y * INV254 };
        int4v ih[4][2], il[4][2];
#pragma unroll
        for (int ms = 0; ms < 4; ++ms)
#pragma unroll
            for (int ns = 0; ns < 2; ++ns) { ih[ms][ns] = (int4v)0; il[ms][ns] = (int4v)0; }
#pragma unroll
        for (int ks = 0; ks < 2; ++ks) {
            const int k0 = g * 128 + ks * 64 + kg * 16;
            int4v a_h[4], a_l[4];
#pragma unroll
            for (int ms = 0; ms < 4; ++ms) {
                a_h[ms] = *(const int4v*)(pAh[ms] + k0);
                a_l[ms] = *(const int4v*)(pAl[ms] + k0);
            }
            const int kp = g * 16 + ks * 8 + kg * 2;
            const int2 q0 = *(const int2*)(wbase + (size_t)kp * NH + c0);
            const int2 q1 = *(const int2*)(wbase + (size_t)(kp + 1) * NH + c0);
            int4v b[2];
            b[0] = unpack16(q0.x, q1.x); b[1] = unpack16(q0.y, q1.y);
#pragma unroll
            for (int ns = 0; ns < 2; ++ns)
#pragma unroll
                for (int ms = 0; ms < 4; ++ms) {
                    ih[ms][ns] = __builtin_amdgcn_mfma_i32_16x16x64_i8(a_h[ms], b[ns], ih[ms][ns], 0, 0, 0);
                    il[ms][ns] = __builtin_amdgcn_mfma_i32_16x16x64_i8(a_l[ms], b[ns], il[ms][ns], 0, 0, 0);
                }
        }
#pragma unroll
        for (int ms = 0; ms < 4; ++ms)
#pragma unroll
            for (int ns = 0; ns < 2; ++ns)
#pragma unroll
                for (int r = 0; r < 4; ++r)
                    facc[ms][ns][r] += sc2[ns] * (float)(__mul24(ih[ms][ns][r], 254) + il[ms][ns][r]);
    }

    if (kh > 0) {
#pragma unroll
        for (int ms = 0; ms < 4; ++ms)
#pragma unroll
            for (int ns = 0; ns < 2; ++ns)
#pragma unroll
                for (int r = 0; r < 4; ++r)
                    red[kh - 1][ms * 16 + kg * 4 + r][lr * 2 + ns] = facc[ms][ns][r];
    }
    __syncthreads();
    if (kh == 0) {
#pragma unroll
        for (int ms = 0; ms < 4; ++ms) {
#pragma unroll
            for (int r = 0; r < 4; ++r) {
                const int rowLoc = ms * 16 + kg * 4 + r;
                const int orow = rb + rowLoc;
                if (orow < me) {
                    const int rg = base + orow;
                    const int t2s = rowmap[rg];
                    const float wscale = topk_w[t2s] * sxa[rg];
#pragma unroll
                    for (int ns = 0; ns < 2; ++ns) {
                        float v = facc[ms][ns][r]
                                + red[0][rowLoc][lr * 2 + ns]
                                + red[1][rowLoc][lr * 2 + ns]
                                + red[2][rowLoc][lr * 2 + ns];
                        // exactly 2 atomic adds per out element -> deterministic
                        atomicAdd(out + (size_t)(t2s >> 1) * NH + c0 + ns, wscale * v);
                    }
                }
            }
        }
    }
}

extern "C" void kernel_launch(void* const* d_in, const int* in_sizes, int n_in,
                              void* d_out, int out_size, void* d_ws, size_t ws_size,
                              hipStream_t stream) {
    const float* x      = (const float*)d_in[0];
    const float* logits = (const float*)d_in[1];
    const int*   w13q   = (const int*)d_in[2];
    const int*   w2q    = (const int*)d_in[3];
    const float* s13    = (const float*)d_in[4];
    const float* s2     = (const float*)d_in[5];

    char* ws = (char*)d_ws;
    size_t o = 0;
    int*   counts   = (int*)(ws + o);   o += 4096;
    int*   offs     = (int*)(ws + o);   o += 4096;
    float* topk_w   = (float*)(ws + o); o += 4096;
    int*   tok_list = (int*)(ws + o);   o += 16384;
    int*   rowmap   = (int*)(ws + o);   o += 4096;
    float* sx       = (float*)(ws + o); o += 4096;
    float* sxa      = (float*)(ws + o); o += 4096;
    char*  xh       = ws + o;           o += (size_t)2 * NT * NH;      // 1 MB sorted
    char*  xl       = ws + o;           o += (size_t)2 * NT * NH;      // 1 MB
    short* a_s      = (short*)(ws + o); o += (size_t)2 * NT * NF * 2;  // 5.77 MB
    char*  ahq      = ws + o;           o += (size_t)2 * NT * NF;      // 2.88 MB
    char*  alq      = ws + o;           o += (size_t)2 * NT * NF;      // 2.88 MB

    hipMemsetAsync(d_out, 0, (size_t)out_size * sizeof(float), stream);
    route_bin_kernel<<<1, 512, 0, stream>>>(logits, topk_w, counts, offs, tok_list, rowmap);
    quant_x_kernel<<<2 * NT, 256, 0, stream>>>(x, rowmap, xh, xl, sx);
    gemm1_act_kernel<<<dim3(NF / 32, 4, NE), 256, 0, stream>>>(
        xh, xl, sx, w13q, s13, counts, offs, a_s);
    quant_a_kernel<<<2 * NT, 256, 0, stream>>>(a_s, ahq, alq, sxa);
    gemm2_kernel<<<dim3(NH / 32, 8, NE), 256, 0, stream>>>(
        ahq, alq, sxa, w2q, s2, counts, offs, rowmap, topk_w, (float*)d_out);
}

// Round 7
// 135.559 us; speedup vs baseline: 1.1422x; 1.1422x over previous
//
#include <hip/hip_runtime.h>
#include <math.h>

#define NE 8
#define NT 512
#define NH 1024
#define NF 2816
#define TWO_F (2*NF)      // 5632
#define HP (NH/8)         // 128 packed rows for w13
#define FP (NF/8)         // 352 packed rows for w2
#define H_GROUPS 8
#define F_GROUPS 22
#define INV254 (1.0f/254.0f)

typedef __attribute__((ext_vector_type(4))) int   int4v;
typedef __attribute__((ext_vector_type(4))) float f32x4;
typedef __attribute__((ext_vector_type(8))) short short8;

__device__ inline short f2bf(float f) {
    unsigned u = __float_as_uint(f);
    u += 0x7FFFu + ((u >> 16) & 1u);   // RNE
    return (short)(u >> 16);
}
__device__ inline float bf2f(short s) {
    return __uint_as_float(((unsigned)(unsigned short)s) << 16);
}

// 16 nibbles (rows kp, kp+1 packed ints) -> 16 int8 bytes = (nib - 8)
__device__ inline int4v unpack16(int q0, int q1) {
    int e0 = q0 & 0x0F0F0F0F, o0 = ((unsigned)q0 >> 4) & 0x0F0F0F0F;
    int e1 = q1 & 0x0F0F0F0F, o1 = ((unsigned)q1 >> 4) & 0x0F0F0F0F;
    int4v b;
    b[0] = (__builtin_amdgcn_perm(o0, e0, 0x05010400) + 0x78787878) ^ 0x80808080;
    b[1] = (__builtin_amdgcn_perm(o0, e0, 0x07030602) + 0x78787878) ^ 0x80808080;
    b[2] = (__builtin_amdgcn_perm(o1, e1, 0x05010400) + 0x78787878) ^ 0x80808080;
    b[3] = (__builtin_amdgcn_perm(o1, e1, 0x07030602) + 0x78787878) ^ 0x80808080;
    return b;
}

__device__ inline int pack4(const int* b) {
    return (b[0] & 255) | ((b[1] & 255) << 8) | ((b[2] & 255) << 16) | ((b[3] & 255) << 24);
}

// ---- routing (softmax->top2->renorm) + stable binning + prefix + rowmap ----
__global__ __launch_bounds__(512) void route_bin_kernel(
        const float* __restrict__ logits,
        float* __restrict__ topk_w,
        int* __restrict__ counts,
        int* __restrict__ offs,
        int* __restrict__ tok_list,
        int* __restrict__ rowmap) {
    __shared__ int sh_e[2 * NT];
    __shared__ int sh_cnt[NE], sh_off[NE];
    const int t = threadIdx.x;   // one token per thread, NT==512
    float l[NE];
#pragma unroll
    for (int e = 0; e < NE; ++e) l[e] = logits[t * NE + e];
    int i0 = 0; float v0 = l[0];
#pragma unroll
    for (int e = 1; e < NE; ++e) { if (l[e] > v0) { v0 = l[e]; i0 = e; } }
    int i1 = -1; float v1 = -INFINITY;
#pragma unroll
    for (int e = 0; e < NE; ++e) {
        if (e == i0) continue;
        if (l[e] > v1) { v1 = l[e]; i1 = e; }
    }
    float e1 = expf(v1 - v0);
    float inv = 1.0f / (1.0f + e1);
    topk_w[t * 2 + 0] = inv;
    topk_w[t * 2 + 1] = e1 * inv;
    sh_e[t * 2 + 0] = i0;
    sh_e[t * 2 + 1] = i1;
    __syncthreads();
    const int w = t >> 6, lane = t & 63;
    int base = 0;
    for (int chunk = 0; chunk < 16; ++chunk) {
        int j = chunk * 64 + lane;
        bool m = (sh_e[j] == w);
        unsigned long long mask = __ballot(m);
        if (m) {
            int pos = base + __popcll(mask & ((1ull << lane) - 1ull));
            tok_list[w * NT + pos] = j;   // j = t*2 + slot
        }
        base += __popcll(mask);
    }
    if (lane == 0) { counts[w] = base; sh_cnt[w] = base; }
    __syncthreads();
    if (t == 0) {
        int o = 0;
#pragma unroll
        for (int e = 0; e < NE; ++e) { sh_off[e] = o; offs[e] = o; o += sh_cnt[e]; }
    }
    __syncthreads();
    const int myoff = sh_off[w];
    for (int i = lane; i < sh_cnt[w]; i += 64)
        rowmap[myoff + i] = tok_list[w * NT + i];   // own wave's writes: safe
}

// -------- gather + x -> dual int8 (hi + lo/254), per-row scale, sorted ------
__global__ __launch_bounds__(256) void quant_x_kernel(const float* __restrict__ x,
                                                      const int* __restrict__ rowmap,
                                                      char* __restrict__ xh,
                                                      char* __restrict__ xl,
                                                      float* __restrict__ sx) {
    __shared__ float wmax[4];
    const int r = blockIdx.x;              // sorted row
    const int t = rowmap[r] >> 1;
    const int tid = threadIdx.x;
    f32x4 v = *(const f32x4*)(x + (size_t)t * NH + tid * 4);
    float m = fmaxf(fmaxf(fabsf(v[0]), fabsf(v[1])), fmaxf(fabsf(v[2]), fabsf(v[3])));
#pragma unroll
    for (int off = 32; off >= 1; off >>= 1)
        m = fmaxf(m, __shfl_xor(m, off, 64));
    if ((tid & 63) == 0) wmax[tid >> 6] = m;
    __syncthreads();
    float amax = fmaxf(fmaxf(wmax[0], wmax[1]), fmaxf(wmax[2], wmax[3]));
    float scale = (amax > 0.f) ? amax / 127.f : 0.f;
    float invs  = (amax > 0.f) ? 127.f / amax : 0.f;
    if (tid == 0) sx[r] = scale;
    int bh[4], bl[4];
#pragma unroll
    for (int j = 0; j < 4; ++j) {
        float xs = v[j] * invs;
        float qh = rintf(xs);
        qh = fminf(fmaxf(qh, -127.f), 127.f);
        float ql = rintf((xs - qh) * 254.f);
        ql = fminf(fmaxf(ql, -127.f), 127.f);
        bh[j] = (int)qh; bl[j] = (int)ql;
    }
    ((int*)xh)[r * (NH / 4) + tid] = pack4(bh);
    ((int*)xl)[r * (NH / 4) + tid] = pack4(bl);
}

// ------- GEMM1 + silu fused (dual int8, weight-prefetch double-buffer) -----
// block 64M x 32F, 4 waves (mh, fh); wave: 32M x 16 g-cols + 16 u-cols
#define G1_LOADW(S, KB) do {                                                  \
    s_scg##S = sb[(size_t)(KB) * TWO_F];                                      \
    s_scu##S = sb[(size_t)(KB) * TWO_F + NF];                                 \
    _Pragma("unroll")                                                         \
    for (int ks = 0; ks < 2; ++ks) {                                          \
        const int kp = (KB) * 16 + ks * 8 + kg * 2;                           \
        q_g##S[ks][0] = wb[(size_t)kp * TWO_F];                               \
        q_g##S[ks][1] = wb[(size_t)(kp + 1) * TWO_F];                         \
        q_u##S[ks][0] = wb[(size_t)kp * TWO_F + NF];                          \
        q_u##S[ks][1] = wb[(size_t)(kp + 1) * TWO_F + NF];                    \
    }                                                                         \
} while (0)

#define G1_COMPUTE(S, KB) do {                                                \
    int4v ah[2][2], al[2][2];                                                 \
    _Pragma("unroll")                                                         \
    for (int ks = 0; ks < 2; ++ks) {                                          \
        const int k0 = (KB) * 128 + ks * 64 + kg * 16;                        \
        _Pragma("unroll")                                                     \
        for (int ms = 0; ms < 2; ++ms) {                                      \
            ah[ks][ms] = *(const int4v*)(pAh[ms] + k0);                       \
            al[ks][ms] = *(const int4v*)(pAl[ms] + k0);                       \
        }                                                                     \
    }                                                                         \
    int4v hg[2] = {(int4v)0, (int4v)0}, lg[2] = {(int4v)0, (int4v)0};         \
    int4v hu[2] = {(int4v)0, (int4v)0}, lu[2] = {(int4v)0, (int4v)0};         \
    _Pragma("unroll")                                                         \
    for (int ks = 0; ks < 2; ++ks) {                                          \
        const int4v bg = unpack16(q_g##S[ks][0], q_g##S[ks][1]);              \
        const int4v bu = unpack16(q_u##S[ks][0], q_u##S[ks][1]);              \
        _Pragma("unroll")                                                     \
        for (int ms = 0; ms < 2; ++ms) {                                      \
            hg[ms] = __builtin_amdgcn_mfma_i32_16x16x64_i8(ah[ks][ms], bg, hg[ms], 0, 0, 0); \
            lg[ms] = __builtin_amdgcn_mfma_i32_16x16x64_i8(al[ks][ms], bg, lg[ms], 0, 0, 0); \
            hu[ms] = __builtin_amdgcn_mfma_i32_16x16x64_i8(ah[ks][ms], bu, hu[ms], 0, 0, 0); \
            lu[ms] = __builtin_amdgcn_mfma_i32_16x16x64_i8(al[ks][ms], bu, lu[ms], 0, 0, 0); \
        }                                                                     \
    }                                                                         \
    const float cg = s_scg##S * INV254, cu = s_scu##S * INV254;               \
    _Pragma("unroll")                                                         \
    for (int ms = 0; ms < 2; ++ms)                                            \
        _Pragma("unroll")                                                     \
        for (int r = 0; r < 4; ++r) {                                         \
            fg[ms][r] += cg * (float)(__mul24(hg[ms][r], 254) + lg[ms][r]);   \
            fu[ms][r] += cu * (float)(__mul24(hu[ms][r], 254) + lu[ms][r]);   \
        }                                                                     \
} while (0)

__global__ __launch_bounds__(256) void gemm1_act_kernel(
        const char*  __restrict__ xh,
        const char*  __restrict__ xl,
        const float* __restrict__ sx,
        const int*   __restrict__ w13q,
        const float* __restrict__ s13,
        const int*   __restrict__ counts,
        const int*   __restrict__ offs,
        short* __restrict__ a_s) {
    const int e = blockIdx.z;
    const int me = counts[e];
    const int mtile = blockIdx.y;
    if (mtile * 64 >= me) return;
    const int base = offs[e];
    const int tid = threadIdx.x;
    const int w = tid >> 6, l = tid & 63;
    const int lr = l & 15, kg = l >> 4;
    const int mh = w >> 1, fh = w & 1;
    const int rb = mtile * 64 + mh * 32;
    const int cF = blockIdx.x * 32 + fh * 16;   // g col = cF+lr, u col = +NF

    const char* pAh[2]; const char* pAl[2];
#pragma unroll
    for (int ms = 0; ms < 2; ++ms) {
        int i = rb + ms * 16 + lr;
        if (i >= me) i = me - 1;
        pAh[ms] = xh + (size_t)(base + i) * NH;
        pAl[ms] = xl + (size_t)(base + i) * NH;
    }

    const int*   wb = w13q + (size_t)e * HP * TWO_F + cF + lr;
    const float* sb = s13  + (size_t)e * H_GROUPS * TWO_F + cF + lr;

    f32x4 fg[2] = {(f32x4)0.f, (f32x4)0.f};
    f32x4 fu[2] = {(f32x4)0.f, (f32x4)0.f};

    int q_gA[2][2], q_uA[2][2], q_gB[2][2], q_uB[2][2];
    float s_scgA, s_scuA, s_scgB, s_scuB;

    G1_LOADW(A, 0);
#pragma unroll
    for (int kb2 = 0; kb2 < 4; ++kb2) {
        const int kb = kb2 * 2;
        G1_LOADW(B, kb + 1);
        G1_COMPUTE(A, kb);
        G1_LOADW(A, (kb + 2 < H_GROUPS) ? kb + 2 : H_GROUPS - 1);
        G1_COMPUTE(B, kb + 1);
    }

    // epilogue: C row = kg*4 + r (+ms*16), col = lr; h = sx[row] * facc
#pragma unroll
    for (int ms = 0; ms < 2; ++ms) {
#pragma unroll
        for (int r = 0; r < 4; ++r) {
            const int orow = rb + ms * 16 + kg * 4 + r;
            if (orow < me) {
                const int rg = base + orow;
                const float sxm = sx[rg];
                const float g = sxm * fg[ms][r];
                const float u = sxm * fu[ms][r];
                const float aval = (g / (1.0f + __expf(-g))) * u;
                a_s[(size_t)rg * NF + cF + lr] = f2bf(aval);
            }
        }
    }
}

// -------- a (bf16, sorted) -> dual int8, per-row scale --------
__global__ __launch_bounds__(256) void quant_a_kernel(const short* __restrict__ a_s,
                                                      char* __restrict__ ah,
                                                      char* __restrict__ al,
                                                      float* __restrict__ sxa) {
    __shared__ float wmax[4];
    const int row = blockIdx.x;            // sorted row 0..1023
    const int tid = threadIdx.x;
    const short* src = a_s + (size_t)row * NF;
    float m = 0.f;
    short8 v[2];
#pragma unroll
    for (int it = 0; it < 2; ++it) {
        const int i = tid + it * 256;
        if (i < NF / 8) {
            v[it] = *(const short8*)(src + i * 8);
#pragma unroll
            for (int j = 0; j < 8; ++j) m = fmaxf(m, fabsf(bf2f(v[it][j])));
        }
    }
#pragma unroll
    for (int off = 32; off >= 1; off >>= 1)
        m = fmaxf(m, __shfl_xor(m, off, 64));
    if ((tid & 63) == 0) wmax[tid >> 6] = m;
    __syncthreads();
    float amax = fmaxf(fmaxf(wmax[0], wmax[1]), fmaxf(wmax[2], wmax[3]));
    float scale = (amax > 0.f) ? amax / 127.f : 0.f;
    float invs  = (amax > 0.f) ? 127.f / amax : 0.f;
    if (tid == 0) sxa[row] = scale;
#pragma unroll
    for (int it = 0; it < 2; ++it) {
        const int i = tid + it * 256;
        if (i < NF / 8) {
            int dh[2], dl[2];
#pragma unroll
            for (int h = 0; h < 2; ++h) {
                int bh[4], bl[4];
#pragma unroll
                for (int j = 0; j < 4; ++j) {
                    float xs = bf2f(v[it][h * 4 + j]) * invs;
                    float qh = rintf(xs);
                    qh = fminf(fmaxf(qh, -127.f), 127.f);
                    float ql = rintf((xs - qh) * 254.f);
                    ql = fminf(fmaxf(ql, -127.f), 127.f);
                    bh[j] = (int)qh; bl[j] = (int)ql;
                }
                dh[h] = pack4(bh); dl[h] = pack4(bl);
            }
            *(int2*)(ah + (size_t)row * NF + i * 8) = make_int2(dh[0], dh[1]);
            *(int2*)(al + (size_t)row * NF + i * 8) = make_int2(dl[0], dl[1]);
        }
    }
}

// ------- GEMM2 (dual int8, prefetch): block 32M x 32N, 4-wave K-split ------
#define G2_LOADW(S, G) do {                                                   \
    _Pragma("unroll")                                                         \
    for (int ns = 0; ns < 2; ++ns)                                            \
        t_sc##S[ns] = s2b[(size_t)(G) * NH + ns * 16];                        \
    _Pragma("unroll")                                                         \
    for (int ks = 0; ks < 2; ++ks) {                                          \
        const int kp = (G) * 16 + ks * 8 + kg * 2;                            \
        _Pragma("unroll")                                                     \
        for (int ns = 0; ns < 2; ++ns) {                                      \
            t_q0##S[ks][ns] = w2b[(size_t)kp * NH + ns * 16];                 \
            t_q1##S[ks][ns] = w2b[(size_t)(kp + 1) * NH + ns * 16];           \
        }                                                                     \
    }                                                                         \
} while (0)

#define G2_COMPUTE(S, G) do {                                                 \
    int4v a_h[2][2], a_l[2][2];                                               \
    _Pragma("unroll")                                                         \
    for (int ks = 0; ks < 2; ++ks) {                                          \
        const int k0 = (G) * 128 + ks * 64 + kg * 16;                         \
        _Pragma("unroll")                                                     \
        for (int ms = 0; ms < 2; ++ms) {                                      \
            a_h[ks][ms] = *(const int4v*)(p2Ah[ms] + k0);                     \
            a_l[ks][ms] = *(const int4v*)(p2Al[ms] + k0);                     \
        }                                                                     \
    }                                                                         \
    int4v ih[2][2], il[2][2];                                                 \
    _Pragma("unroll")                                                         \
    for (int ms = 0; ms < 2; ++ms)                                            \
        _Pragma("unroll")                                                     \
        for (int ns = 0; ns < 2; ++ns) { ih[ms][ns] = (int4v)0; il[ms][ns] = (int4v)0; } \
    _Pragma("unroll")                                                         \
    for (int ks = 0; ks < 2; ++ks) {                                          \
        _Pragma("unroll")                                                     \
        for (int ns = 0; ns < 2; ++ns) {                                      \
            const int4v b = unpack16(t_q0##S[ks][ns], t_q1##S[ks][ns]);       \
            _Pragma("unroll")                                                 \
            for (int ms = 0; ms < 2; ++ms) {                                  \
                ih[ms][ns] = __builtin_amdgcn_mfma_i32_16x16x64_i8(a_h[ks][ms], b, ih[ms][ns], 0, 0, 0); \
                il[ms][ns] = __builtin_amdgcn_mfma_i32_16x16x64_i8(a_l[ks][ms], b, il[ms][ns], 0, 0, 0); \
            }                                                                 \
        }                                                                     \
    }                                                                         \
    _Pragma("unroll")                                                         \
    for (int ns = 0; ns < 2; ++ns) {                                          \
        const float c = t_sc##S[ns] * INV254;                                 \
        _Pragma("unroll")                                                     \
        for (int ms = 0; ms < 2; ++ms)                                        \
            _Pragma("unroll")                                                 \
            for (int r = 0; r < 4; ++r)                                       \
                facc[ms][ns][r] += c * (float)(__mul24(ih[ms][ns][r], 254) + il[ms][ns][r]); \
    }                                                                         \
} while (0)

__global__ __launch_bounds__(256) void gemm2_kernel(
        const char*  __restrict__ ahq,
        const char*  __restrict__ alq,
        const float* __restrict__ sxa,
        const int*   __restrict__ w2q,
        const float* __restrict__ s2,
        const int*   __restrict__ counts,
        const int*   __restrict__ offs,
        const int*   __restrict__ rowmap,
        const float* __restrict__ topk_w,
        float* __restrict__ out) {
    __shared__ float red[3][32][33];
    const int e = blockIdx.z;
    const int me = counts[e];
    const int mtile = blockIdx.y;
    if (mtile * 32 >= me) return;
    const int base = offs[e];
    const int tid = threadIdx.x;
    const int kh = tid >> 6, l = tid & 63;
    const int lr = l & 15, kg = l >> 4;
    const int rb = mtile * 32;
    const int cb = blockIdx.x * 32;

    const char* p2Ah[2]; const char* p2Al[2];
#pragma unroll
    for (int ms = 0; ms < 2; ++ms) {
        int i = rb + ms * 16 + lr;
        if (i >= me) i = me - 1;
        p2Ah[ms] = ahq + (size_t)(base + i) * NF;
        p2Al[ms] = alq + (size_t)(base + i) * NF;
    }

    const int*   w2b = w2q + (size_t)e * FP * NH + cb + lr;
    const float* s2b = s2  + (size_t)e * F_GROUPS * NH + cb + lr;

    f32x4 facc[2][2];
#pragma unroll
    for (int ms = 0; ms < 2; ++ms)
#pragma unroll
        for (int ns = 0; ns < 2; ++ns) facc[ms][ns] = (f32x4)0.f;

    int t_q0A[2][2], t_q1A[2][2], t_q0B[2][2], t_q1B[2][2];
    float t_scA[2], t_scB[2];

    const int glast = kh + 4 * ((F_GROUPS - 1 - kh) >> 2);
    G2_LOADW(A, kh);
#pragma unroll
    for (int it = 0; it < 3; ++it) {
        const int g0 = kh + it * 8;
        if (g0 <= glast) {
            const int gn = (g0 + 4 <= glast) ? g0 + 4 : glast;
            G2_LOADW(B, gn);
            G2_COMPUTE(A, g0);
        }
        if (g0 + 4 <= glast) {
            const int gn = (g0 + 8 <= glast) ? g0 + 8 : glast;
            G2_LOADW(A, gn);
            G2_COMPUTE(B, g0 + 4);
        }
    }

    if (kh > 0) {
#pragma unroll
        for (int ms = 0; ms < 2; ++ms)
#pragma unroll
            for (int ns = 0; ns < 2; ++ns)
#pragma unroll
                for (int r = 0; r < 4; ++r)
                    red[kh - 1][ms * 16 + kg * 4 + r][ns * 16 + lr] = facc[ms][ns][r];
    }
    __syncthreads();
    if (kh == 0) {
#pragma unroll
        for (int ms = 0; ms < 2; ++ms) {
#pragma unroll
            for (int r = 0; r < 4; ++r) {
                const int rowLoc = ms * 16 + kg * 4 + r;
                const int orow = rb + rowLoc;
                if (orow < me) {
                    const int rg = base + orow;
                    const int t2s = rowmap[rg];
                    const float wscale = topk_w[t2s] * sxa[rg];
#pragma unroll
                    for (int ns = 0; ns < 2; ++ns) {
                        float v = facc[ms][ns][r]
                                + red[0][rowLoc][ns * 16 + lr]
                                + red[1][rowLoc][ns * 16 + lr]
                                + red[2][rowLoc][ns * 16 + lr];
                        // exactly 2 atomic adds per out element -> deterministic
                        atomicAdd(out + (size_t)(t2s >> 1) * NH + cb + ns * 16 + lr, wscale * v);
                    }
                }
            }
        }
    }
}

extern "C" void kernel_launch(void* const* d_in, const int* in_sizes, int n_in,
                              void* d_out, int out_size, void* d_ws, size_t ws_size,
                              hipStream_t stream) {
    const float* x      = (const float*)d_in[0];
    const float* logits = (const float*)d_in[1];
    const int*   w13q   = (const int*)d_in[2];
    const int*   w2q    = (const int*)d_in[3];
    const float* s13    = (const float*)d_in[4];
    const float* s2     = (const float*)d_in[5];

    char* ws = (char*)d_ws;
    size_t o = 0;
    int*   counts   = (int*)(ws + o);   o += 4096;
    int*   offs     = (int*)(ws + o);   o += 4096;
    float* topk_w   = (float*)(ws + o); o += 4096;
    int*   tok_list = (int*)(ws + o);   o += 16384;
    int*   rowmap   = (int*)(ws + o);   o += 4096;
    float* sx       = (float*)(ws + o); o += 4096;
    float* sxa      = (float*)(ws + o); o += 4096;
    char*  xh       = ws + o;           o += (size_t)2 * NT * NH;      // 1 MB sorted
    char*  xl       = ws + o;           o += (size_t)2 * NT * NH;      // 1 MB
    short* a_s      = (short*)(ws + o); o += (size_t)2 * NT * NF * 2;  // 5.77 MB
    char*  ahq      = ws + o;           o += (size_t)2 * NT * NF;      // 2.88 MB
    char*  alq      = ws + o;           o += (size_t)2 * NT * NF;      // 2.88 MB

    hipMemsetAsync(d_out, 0, (size_t)out_size * sizeof(float), stream);
    route_bin_kernel<<<1, 512, 0, stream>>>(logits, topk_w, counts, offs, tok_list, rowmap);
    quant_x_kernel<<<2 * NT, 256, 0, stream>>>(x, rowmap, xh, xl, sx);
    gemm1_act_kernel<<<dim3(NF / 32, 8, NE), 256, 0, stream>>>(
        xh, xl, sx, w13q, s13, counts, offs, a_s);
    quant_a_kernel<<<2 * NT, 256, 0, stream>>>(a_s, ahq, alq, sxa);
    gemm2_kernel<<<dim3(NH / 32, 16, NE), 256, 0, stream>>>(
        ahq, alq, sxa, w2q, s2, counts, offs, rowmap, topk_w, (float*)d_out);
}